// Round 8
// baseline (257.717 us; speedup 1.0000x reference)
//
#include <hip/hip_runtime.h>
#include <hip/hip_bf16.h>

// Problem: B=2, S=2048, D_MODEL=1024, H=16, DK=64.
// out = ((l2norm(Q Wq^T) l2norm(K Wk^T)^T)^2 (V Wv^T)) Wo^T   (per head)
// fp32 in/out; internally bf16 MFMA with fp32 accumulation.
//
// Round 16 = Round 15 resubmitted verbatim (bench infra failed; kernel
// re-audited: no OOB, no divergent barrier, vmcnt ledger coherent).
//  - qkv: fp32->bf16 conversion of Q/K/V FUSED into the GEMM A-path.
//    A is read as fp32 via 8x global_load_dwordx4 (issue-early), converted
//    in-reg, ds_write_b128 into the same swizzled LDS layout. W stays
//    global_load_lds bf16. Counted vmcnt: steady state {A-regs:8, W:4}.
//    This deletes the 75 MB Q/K/V portion of convert_kernel.
//  - convert_kernel: weights + biases only (8 tensors, ~25 MB, ~5us).
//  - wo: BM=128 (256 blocks = 1/CU, no scheduling tail, 2x MFMA/byte).

#define D_MODEL 1024
#define N_HEADS 16
#define D_K     64
#define BATCH   2
#define SEQ     2048
#define M_TOT   (BATCH * SEQ)   // 4096

typedef short  s16x8 __attribute__((ext_vector_type(8)));   // 8 bf16 = 4 VGPR
typedef short  s16x4 __attribute__((ext_vector_type(4)));   // 4 bf16 = 2 VGPR
typedef float  f32x4 __attribute__((ext_vector_type(4)));   // MFMA C/D frag
typedef unsigned short ushort_t;
typedef ushort_t us4 __attribute__((ext_vector_type(4)));
typedef ushort_t us8 __attribute__((ext_vector_type(8)));

__device__ __forceinline__ ushort_t f2bf(float f) {
    union { float f; unsigned int u; } x; x.f = f;
    unsigned int u = x.u;
    return (ushort_t)((u + 0x7fffu + ((u >> 16) & 1u)) >> 16);  // RNE
}
__device__ __forceinline__ float bf2f(ushort_t h) {
    union { unsigned int u; float f; } x; x.u = ((unsigned int)h) << 16;
    return x.f;
}
// pack two fp32 -> u32 of two bf16 (RNE)
__device__ __forceinline__ unsigned int pack2bf(float a, float b) {
    union { __hip_bfloat162 h; unsigned int u; } x;
    x.h = __float22bfloat162_rn(float2{a, b});
    return x.u;
}

// PV matrix op: K=16 bf16 MFMA (B-frag == squared QK^T D-frag, in-lane).
__device__ __forceinline__ f32x4 mfma_pv(s16x4 a, s16x4 b, f32x4 c) {
#if __has_builtin(__builtin_amdgcn_mfma_f32_16x16x16bf16_1k)
    return __builtin_amdgcn_mfma_f32_16x16x16bf16_1k(a, b, c, 0, 0, 0);
#else
    // zero-padded K=32 fallback: real data in k=quad*8+0..3 on both sides
    s16x8 a8 = {a[0], a[1], a[2], a[3], 0, 0, 0, 0};
    s16x8 b8 = {b[0], b[1], b[2], b[3], 0, 0, 0, 0};
    return __builtin_amdgcn_mfma_f32_16x16x32_bf16(a8, b8, c, 0, 0, 0);
#endif
}

// async global->LDS, 16B per lane (lane i's lds ptr == wave base + i*16).
__device__ __forceinline__ void gload_lds16(const ushort_t* g, ushort_t* l) {
    __builtin_amdgcn_global_load_lds(
        (__attribute__((address_space(1))) void*)(ushort_t*)g,
        (__attribute__((address_space(3))) void*)l, 16, 0, 0);
}

#define WAIT_VM(n)  asm volatile("s_waitcnt vmcnt(" #n ")" ::: "memory")
#define WAIT_LGKM0  asm volatile("s_waitcnt lgkmcnt(0)" ::: "memory")
#define BARRIER     asm volatile("s_barrier" ::: "memory")

// ---------------------------------------------------------------------------
// fp32 -> bf16 conversion: weights + biases only (8 tensors).
// ---------------------------------------------------------------------------
struct ConvArgs {
    const float* src[8];
    ushort_t*    dst[8];
    int          n[8];
    int          cum[9];   // chunk prefix sums (2048-elem chunks)
};

__global__ __launch_bounds__(256) void convert_kernel(ConvArgs a) {
    const int lin = blockIdx.x;
    int t = 0;
#pragma unroll
    for (int i = 0; i < 8; ++i)
        if (lin >= a.cum[i + 1]) t = i + 1;
    const int off = (lin - a.cum[t]) * 2048 + threadIdx.x * 8;
    if (off >= a.n[t]) return;
    const float4 v0 = *(const float4*)(a.src[t] + off);
    const float4 v1 = *(const float4*)(a.src[t] + off + 4);
    us8 p;
    p[0] = f2bf(v0.x); p[1] = f2bf(v0.y); p[2] = f2bf(v0.z); p[3] = f2bf(v0.w);
    p[4] = f2bf(v1.x); p[5] = f2bf(v1.y); p[6] = f2bf(v1.z); p[7] = f2bf(v1.w);
    *(us8*)(a.dst[t] + off) = p;
}

// ---------------------------------------------------------------------------
// GEMM body (bf16 A via gload_lds) — used by wo. BM x 128 tile, 4 waves 2x2,
// 2-deep DMA pipeline, BK=64, issue-early staging. MODE 0: fp32 store.
// ---------------------------------------------------------------------------
template <int BM, int MODE>
__device__ __forceinline__ void gemm_body(
    ushort_t* __restrict__ smem,
    const ushort_t* __restrict__ A,
    const ushort_t* __restrict__ W,
    const ushort_t* __restrict__ bias,
    ushort_t* __restrict__ out,
    float* __restrict__ outf,
    int bx, int by)
{
    static_assert(BM == 64 || BM == 128, "");
    constexpr int K    = 1024;
    constexpr int MF   = BM / 32;
    constexpr int BUFW = (BM + 128) * 64;
    constexpr int NIT  = K / 64;

    const int t    = threadIdx.x;
    const int wave = t >> 6;
    const int lane = t & 63;
    const int quad = lane >> 4;
    const int lc   = lane & 15;
    const int wm   = wave >> 1;
    const int wn   = wave & 1;
    const int m0   = bx * BM;
    const int n0   = by * 128;

    f32x4 acc[MF][4];
    const f32x4 zero = {0.f, 0.f, 0.f, 0.f};
#pragma unroll
    for (int i = 0; i < MF; ++i)
#pragma unroll
        for (int j = 0; j < 4; ++j) acc[i][j] = zero;

    auto stage = [&](int buf, int k0) {
        ushort_t* Ast = smem + buf * BUFW;
        ushort_t* Bst = Ast + BM * 64;
#pragma unroll
        for (int c = 0; c < MF; ++c) {
            int idx = c * 256 + t;
            int row = idx >> 3, phys = idx & 7;
            int col = (phys ^ (row & 7)) * 8;
            gload_lds16(A + (size_t)(m0 + row) * K + k0 + col, Ast + idx * 8);
        }
#pragma unroll
        for (int c = 0; c < 4; ++c) {
            int idx = c * 256 + t;
            int row = idx >> 3, phys = idx & 7;
            int col = (phys ^ (row & 7)) * 8;
            gload_lds16(W + (size_t)(n0 + row) * K + k0 + col, Bst + idx * 8);
        }
    };
    auto loadfrags = [&](int buf, s16x8 (&a)[MF][2], s16x8 (&b)[4][2]) {
        ushort_t* Ast = smem + buf * BUFW;
        ushort_t* Bst = Ast + BM * 64;
#pragma unroll
        for (int ks = 0; ks < 2; ++ks) {
            const int ph = ((ks * 4 + quad) ^ (lc & 7)) * 8;
#pragma unroll
            for (int i = 0; i < MF; ++i)
                a[i][ks] = *(const s16x8*)(Ast + (wm * (BM / 2) + i * 16 + lc) * 64 + ph);
#pragma unroll
            for (int i = 0; i < 4; ++i)
                b[i][ks] = *(const s16x8*)(Bst + (wn * 64 + i * 16 + lc) * 64 + ph);
        }
    };
    auto mfmas = [&](s16x8 (&a)[MF][2], s16x8 (&b)[4][2]) {
#pragma unroll
        for (int ks = 0; ks < 2; ++ks)
#pragma unroll
            for (int mf = 0; mf < MF; ++mf)
#pragma unroll
                for (int nf = 0; nf < 4; ++nf)
                    acc[mf][nf] = __builtin_amdgcn_mfma_f32_16x16x32_bf16(
                        a[mf][ks], b[nf][ks], acc[mf][nf], 0, 0, 0);
    };

    stage(0, 0);
    stage(1, 64);
    s16x8 afr[MF][2], bfr[4][2];
    for (int it = 0; it < NIT; ++it) {
        if (it < NIT - 1) {
            if constexpr (BM == 128) WAIT_VM(8); else WAIT_VM(6);
        } else {
            WAIT_VM(0);
        }
        BARRIER;                       // tile `it` landed
        loadfrags(it & 1, afr, bfr);
        WAIT_LGKM0;
        BARRIER;                       // all waves' reads done -> buf reusable
        if (it < NIT - 2) stage(it & 1, (it + 2) * 64);   // issue-early DMA
        mfmas(afr, bfr);               // covers the DMA flight
    }

    float bv[4];
#pragma unroll
    for (int nf = 0; nf < 4; ++nf) bv[nf] = bf2f(bias[n0 + wn * 64 + nf * 16 + lc]);

    if (MODE == 0) {
#pragma unroll
        for (int mf = 0; mf < MF; ++mf)
#pragma unroll
            for (int nf = 0; nf < 4; ++nf)
#pragma unroll
                for (int r = 0; r < 4; ++r) {
                    int mg = m0 + wm * (BM / 2) + mf * 16 + quad * 4 + r;
                    int ng = n0 + wn * 64 + nf * 16 + lc;
                    outf[(size_t)mg * D_MODEL + ng] = acc[mf][nf][r] + bv[nf];
                }
    }
}

// ---------------------------------------------------------------------------
// Fused GEMM body for qkv: A is fp32 (conversion fused into staging).
// Per stage: 8x global_load_dwordx4 (fp32 A, issue-early) -> cvt -> 4x
// ds_write_b128 into the swizzled LDS layout; W via gload_lds16 (bf16).
// Steady-state outstanding VMEM: {A-regs(it+1): 8, W(it+1): 4}.
// MODE 1: L2-norm -> (B,H,S,DK)   MODE 2: transpose -> (B,H,DK,S)
// ---------------------------------------------------------------------------
template <int MODE>
__device__ __forceinline__ void gemm_fused_body(
    ushort_t* __restrict__ smem,
    const float* __restrict__ Af,
    const ushort_t* __restrict__ W,
    const ushort_t* __restrict__ bias,
    ushort_t* __restrict__ out,
    int bx, int by)
{
    constexpr int BM   = 128;
    constexpr int K    = 1024;
    constexpr int MF   = 4;
    constexpr int BUFW = (128 + 128) * 64;
    constexpr int NIT  = 16;

    const int t    = threadIdx.x;
    const int wave = t >> 6;
    const int lane = t & 63;
    const int quad = lane >> 4;
    const int lc   = lane & 15;
    const int wm   = wave >> 1;
    const int wn   = wave & 1;
    const int m0   = bx * BM;
    const int n0   = by * 128;

    f32x4 acc[MF][4];
    const f32x4 zero = {0.f, 0.f, 0.f, 0.f};
#pragma unroll
    for (int i = 0; i < MF; ++i)
#pragma unroll
        for (int j = 0; j < 4; ++j) acc[i][j] = zero;

    float4 ar[8];                      // in-flight A fp32 regs (32 VGPR)
    auto loadA = [&](int k0) {
#pragma unroll
        for (int c = 0; c < 4; ++c) {
            int idx = c * 256 + t;
            int row = idx >> 3, phys = idx & 7;
            int col = (phys ^ (row & 7)) * 8;
            const float* src = Af + (size_t)(m0 + row) * K + k0 + col;
            ar[c * 2]     = *(const float4*)(src);
            ar[c * 2 + 1] = *(const float4*)(src + 4);
        }
    };
    auto writeA = [&](int buf) {
        ushort_t* Ast = smem + buf * BUFW;
#pragma unroll
        for (int c = 0; c < 4; ++c) {
            int idx = c * 256 + t;
            us8 p;
            p[0] = f2bf(ar[c * 2].x);     p[1] = f2bf(ar[c * 2].y);
            p[2] = f2bf(ar[c * 2].z);     p[3] = f2bf(ar[c * 2].w);
            p[4] = f2bf(ar[c * 2 + 1].x); p[5] = f2bf(ar[c * 2 + 1].y);
            p[6] = f2bf(ar[c * 2 + 1].z); p[7] = f2bf(ar[c * 2 + 1].w);
            *(us8*)(Ast + idx * 8) = p;
        }
    };
    auto stageW = [&](int buf, int k0) {
        ushort_t* Bst = smem + buf * BUFW + BM * 64;
#pragma unroll
        for (int c = 0; c < 4; ++c) {
            int idx = c * 256 + t;
            int row = idx >> 3, phys = idx & 7;
            int col = (phys ^ (row & 7)) * 8;
            gload_lds16(W + (size_t)(n0 + row) * K + k0 + col, Bst + idx * 8);
        }
    };
    auto loadfrags = [&](int buf, s16x8 (&a)[MF][2], s16x8 (&b)[4][2]) {
        ushort_t* Ast = smem + buf * BUFW;
        ushort_t* Bst = Ast + BM * 64;
#pragma unroll
        for (int ks = 0; ks < 2; ++ks) {
            const int ph = ((ks * 4 + quad) ^ (lc & 7)) * 8;
#pragma unroll
            for (int i = 0; i < MF; ++i)
                a[i][ks] = *(const s16x8*)(Ast + (wm * 64 + i * 16 + lc) * 64 + ph);
#pragma unroll
            for (int i = 0; i < 4; ++i)
                b[i][ks] = *(const s16x8*)(Bst + (wn * 64 + i * 16 + lc) * 64 + ph);
        }
    };
    auto mfmas = [&](s16x8 (&a)[MF][2], s16x8 (&b)[4][2]) {
#pragma unroll
        for (int ks = 0; ks < 2; ++ks)
#pragma unroll
            for (int mf = 0; mf < MF; ++mf)
#pragma unroll
                for (int nf = 0; nf < 4; ++nf)
                    acc[mf][nf] = __builtin_amdgcn_mfma_f32_16x16x32_bf16(
                        a[mf][ks], b[nf][ks], acc[mf][nf], 0, 0, 0);
    };

    // prologue: establish steady-state invariant {A(1):8, W(1):4} at loop top
    loadA(0);                          // 8 vmem
    stageW(0, 0);                      // 4 vmem
    WAIT_VM(4);                        // A(0) regs landed (W(0) may fly)
    writeA(0);
    loadA(64);                         // 8
    stageW(1, 64);                     // 4  -> outstanding {W0:4, A1:8, W1:4}
    WAIT_VM(12);                       // W(0) landed
    WAIT_LGKM0;
    BARRIER;                           // buf0 complete everywhere

    s16x8 afr[MF][2], bfr[4][2];
    for (int it = 0; it < NIT; ++it) {
        loadfrags(it & 1, afr, bfr);   // ds_reads of tile it
        if (it < NIT - 1) {
            WAIT_VM(4);                // A-regs(it+1) landed
            writeA((it + 1) & 1);
            WAIT_VM(0);                // W(it+1) landed (issued a full iter ago)
        }
        WAIT_LGKM0;                    // my frag reads + A writes done
        BARRIER;                       // buf it+1 ready; buf it free
        if (it < NIT - 2) {
            loadA((it + 2) * 64);      // 8, issue-early
            stageW(it & 1, (it + 2) * 64);  // 4
        }
        mfmas(afr, bfr);               // covers DMA flight
    }

    float bv[4];
#pragma unroll
    for (int nf = 0; nf < 4; ++nf) bv[nf] = bf2f(bias[n0 + wn * 64 + nf * 16 + lc]);

    if (MODE == 1) {
#pragma unroll
        for (int mf = 0; mf < MF; ++mf)
#pragma unroll
            for (int r = 0; r < 4; ++r) {
                float ss = 0.f;
#pragma unroll
                for (int nf = 0; nf < 4; ++nf) {
                    float v = acc[mf][nf][r] + bv[nf];
                    acc[mf][nf][r] = v;
                    ss += v * v;
                }
                ss += __shfl_xor(ss, 1);
                ss += __shfl_xor(ss, 2);
                ss += __shfl_xor(ss, 4);
                ss += __shfl_xor(ss, 8);
                float inv = rsqrtf(ss + 1e-8f);
                int mg = m0 + wm * 64 + mf * 16 + quad * 4 + r;
                int b  = mg >> 11;
                int s  = mg & 2047;
#pragma unroll
                for (int nf = 0; nf < 4; ++nf) {
                    int ng = n0 + wn * 64 + nf * 16 + lc;
                    int h = ng >> 6, d = ng & 63;
                    out[(((size_t)(b * N_HEADS + h)) * SEQ + s) * D_K + d] =
                        f2bf(acc[mf][nf][r] * inv);
                }
            }
    } else {
        __syncthreads();
        ushort_t* vt = smem + wave * (64 * 72);
#pragma unroll
        for (int mf = 0; mf < 4; ++mf)
#pragma unroll
            for (int nf = 0; nf < 4; ++nf) {
                us4 p;
#pragma unroll
                for (int r = 0; r < 4; ++r) p[r] = f2bf(acc[mf][nf][r] + bv[nf]);
                *(us4*)(vt + (nf * 16 + lc) * 72 + mf * 16 + quad * 4) = p;
            }
        WAIT_LGKM0;
        __syncthreads();
#pragma unroll
        for (int r = 0; r < 8; ++r) {
            int d  = r * 8 + (lane >> 3);
            int so = (lane & 7) * 8;
            uint4 val = *(const uint4*)(vt + d * 72 + so);
            int mg = m0 + wm * 64 + so;
            int b  = mg >> 11;
            int s  = mg & 2047;
            int ng = n0 + wn * 64 + d;
            int h = ng >> 6, dh = ng & 63;
            *(uint4*)(out + (((size_t)(b * N_HEADS + h)) * D_K + dh) * SEQ + s) = val;
        }
    }
}

// qkv: 1-D grid 768; lin%8 = N-panel (by) -> XCD-resident W panel.
__global__ __launch_bounds__(256) void qkv_kernel(
    const float* __restrict__ Qf, const float* __restrict__ Kf,
    const float* __restrict__ Vf,
    const ushort_t* __restrict__ Wq, const ushort_t* __restrict__ Wk,
    const ushort_t* __restrict__ Wv,
    const ushort_t* __restrict__ bq, const ushort_t* __restrict__ bk,
    const ushort_t* __restrict__ bv,
    ushort_t* __restrict__ qn, ushort_t* __restrict__ kn,
    ushort_t* __restrict__ vT)
{
    __shared__ __align__(16) ushort_t smem[2 * (128 + 128) * 64];  // 64 KB
    const int lin = blockIdx.x;
    const int by  = lin & 7;
    const int r   = lin >> 3;          // 0..95
    const int bx  = r & 31;
    const int z   = r >> 5;            // 0..2
    if (z == 0)
        gemm_fused_body<1>(smem, Qf, Wq, bq, qn, bx, by);
    else if (z == 1)
        gemm_fused_body<1>(smem, Kf, Wk, bk, kn, bx, by);
    else
        gemm_fused_body<2>(smem, Vf, Wv, bv, vT, bx, by);
}

// wo: 1-D grid 256; lin%8 = N-panel; BM=128.
__global__ __launch_bounds__(256) void wo_kernel(
    const ushort_t* __restrict__ A, const ushort_t* __restrict__ W,
    const ushort_t* __restrict__ bias, float* __restrict__ outf)
{
    __shared__ __align__(16) ushort_t smem[2 * (128 + 128) * 64];  // 64 KB
    const int lin = blockIdx.x;
    gemm_body<128, 0>(smem, A, W, bias, nullptr, outf, lin >> 3, lin & 7);
}

// ---------------------------------------------------------------------------
// Attention (unchanged; best measured variant): per (b,h): out = (qn kn^T)^2 v.
// Grid (x=bh 32, y=qt 16) -> 512 blocks; bh%8 XCD pin. 128 q/block.
// ---------------------------------------------------------------------------
__global__ __launch_bounds__(256, 2) void attn_kernel(
    const ushort_t* __restrict__ qn,
    const ushort_t* __restrict__ kn,
    const ushort_t* __restrict__ vT,
    ushort_t* __restrict__ attn_out)
{
    // staging buf i at smem+i*8192: kst [64 j][64 dk] + vst [64 d][64 j]
    // (both 8-el-chunk XOR-swizzled). Epilogue overlays f32 red buf.
    __shared__ __align__(16) ushort_t smem[4 * 8192];   // 64 KB

    const int t    = threadIdx.x;
    const int wave = t >> 6;
    const int lane = t & 63;
    const int quad = lane >> 4;
    const int lc   = lane & 15;
    const int bh   = blockIdx.x;       // 0..31 (bh%8 -> XCD pin)
    const int qt   = blockIdx.y;       // 0..15
    const int b    = bh >> 4;
    const int h    = bh & 15;

    const ushort_t* qb = qn + (size_t)bh * SEQ * D_K;
    const ushort_t* kb = kn + (size_t)bh * SEQ * D_K;
    const ushort_t* vb = vT + (size_t)bh * D_K * SEQ;
    const int q0 = qt * 128;

    // Q B-frags for all 8 q-tiles of this block, reused over 32 k-tiles
    s16x8 qf[8][2];
#pragma unroll
    for (int mf = 0; mf < 8; ++mf)
#pragma unroll
        for (int ks = 0; ks < 2; ++ks)
            qf[mf][ks] = *(const s16x8*)(qb + (size_t)(q0 + mf * 16 + lc) * D_K +
                                         ks * 32 + quad * 8);

    // wave's partial O^T[64 d][128 q]: oacc[df][mf], lane(lc,quad) reg r =
    // O^T[d = df*16 + quad*4 + r][q = mf*16 + lc]
    f32x4 oacc[4][8];
    const f32x4 zero = {0.f, 0.f, 0.f, 0.f};
#pragma unroll
    for (int df = 0; df < 4; ++df)
#pragma unroll
        for (int mf = 0; mf < 8; ++mf) oacc[df][mf] = zero;

    auto stage = [&](int buf, int j0) {
        ushort_t* kst = smem + buf * 8192;
        ushort_t* vst = kst + 4096;
#pragma unroll
        for (int c = 0; c < 2; ++c) {
            int idx = c * 256 + t;
            int row = idx >> 3, phys = idx & 7;
            int col = (phys ^ (row & 7)) * 8;
            gload_lds16(kb + (size_t)(j0 + row) * D_K + col, kst + idx * 8);
            gload_lds16(vb + (size_t)row * SEQ + j0 + col, vst + idx * 8);
        }
    };

    auto compute = [&](int buf) {
        ushort_t* kst = smem + buf * 8192;
        ushort_t* vst = kst + 4096;
        // K A-frags for wave's 16-j slice (K=32 over dk)
        s16x8 ak[2];
#pragma unroll
        for (int ks = 0; ks < 2; ++ks)
            ak[ks] = *(const s16x8*)(kst + (wave * 16 + lc) * 64 +
                                     (((ks * 4 + quad) ^ (lc & 7)) * 8));
        // V^T A-frags (K=16 over wave's j-slice): lane(lc,quad) needs
        // V^T[d = df*16+lc][j = wave*16 + quad*4 + 0..3] -> b64 read
        s16x4 av[4];
#pragma unroll
        for (int df = 0; df < 4; ++df) {
            const int d  = df * 16 + lc;
            const int cj = wave * 2 + (quad >> 1);        // logical 8-el chunk
            av[df] = *(const s16x4*)(vst + d * 64 + ((cj ^ (d & 7)) << 3) +
                                     ((quad & 1) << 2));
        }
#pragma unroll
        for (int mf = 0; mf < 8; ++mf) {
            f32x4 st = zero;   // S^T tile: lane = [j=quad*4+r][q=lc]
#pragma unroll
            for (int ks = 0; ks < 2; ++ks)
                st = __builtin_amdgcn_mfma_f32_16x16x32_bf16(ak[ks], qf[mf][ks],
                                                             st, 0, 0, 0);
            // square + pack: D-frag -> B-frag of K=16 MFMA, in-lane
            union { unsigned int u[2]; s16x4 v; } pb;
            pb.u[0] = pack2bf(st[0] * st[0], st[1] * st[1]);
            pb.u[1] = pack2bf(st[2] * st[2], st[3] * st[3]);
#pragma unroll
            for (int df = 0; df < 4; ++df)
                oacc[df][mf] = mfma_pv(av[df], pb.v, oacc[df][mf]);
        }
    };

    constexpr int NT = 32;
    stage(0, 0);
    stage(1, 64);
    stage(2, 128);
    for (int it = 0; it < NT; ++it) {
        if (it < NT - 2)      { WAIT_VM(8); }
        else if (it == NT - 2){ WAIT_VM(4); }
        else                  { WAIT_VM(0); }
        BARRIER;                       // tile `it` landed everywhere
        compute(it & 3);
        if (it < NT - 3) stage((it + 3) & 3, (it + 3) * 64);
    }

    // 4-wave reduction of O^T partials + store, 8 chunks of 16 q.
    // red[w][d][q], q-pitch 17 to break 4-way write aliasing. 17.4 KB.
    float* red = (float*)smem;
    constexpr int RP = 17;
#pragma unroll
    for (int mf = 0; mf < 8; ++mf) {
        BARRIER;                       // previous chunk's reads (or loop) done
#pragma unroll
        for (int df = 0; df < 4; ++df)
#pragma unroll
            for (int r = 0; r < 4; ++r)
                red[(wave * 64 + df * 16 + quad * 4 + r) * RP + lc] =
                    oacc[df][mf][r];
        WAIT_LGKM0;
        BARRIER;                       // all partials visible
#pragma unroll
        for (int qq = 0; qq < 4; ++qq) {
            const int q = wave * 4 + qq;
            const int d = lane;
            float v = red[(0 * 64 + d) * RP + q] + red[(1 * 64 + d) * RP + q] +
                      red[(2 * 64 + d) * RP + q] + red[(3 * 64 + d) * RP + q];
            const int s = q0 + mf * 16 + q;
            attn_out[((size_t)(b * SEQ + s)) * D_MODEL + h * D_K + d] = f2bf(v);
        }
    }
}

extern "C" void kernel_launch(void* const* d_in, const int* in_sizes, int n_in,
                              void* d_out, int out_size, void* d_ws, size_t ws_size,
                              hipStream_t stream)
{
    const float* Qf   = (const float*)d_in[0];
    const float* Kf   = (const float*)d_in[1];
    const float* Vf   = (const float*)d_in[2];
    const float* Wqf  = (const float*)d_in[3];
    const float* Wqbf = (const float*)d_in[4];
    const float* Wkf  = (const float*)d_in[5];
    const float* Wkbf = (const float*)d_in[6];
    const float* Wvf  = (const float*)d_in[7];
    const float* Wvbf = (const float*)d_in[8];
    const float* Wof  = (const float*)d_in[9];
    const float* Wobf = (const float*)d_in[10];

    const size_t NM = (size_t)M_TOT * D_MODEL;
    const size_t NW = (size_t)D_MODEL * D_MODEL;
    const size_t NB = D_MODEL;

    ushort_t* p = (ushort_t*)d_ws;
    ushort_t* Wq  = p;  p += NW;
    ushort_t* Wk  = p;  p += NW;
    ushort_t* Wv  = p;  p += NW;
    ushort_t* Wo  = p;  p += NW;
    ushort_t* bq  = p;  p += NB;
    ushort_t* bk  = p;  p += NB;
    ushort_t* bvv = p;  p += NB;
    ushort_t* bo  = p;  p += NB;
    ushort_t* qn  = p;  p += NM;   // (B,H,S,DK)
    ushort_t* kn  = p;  p += NM;   // (B,H,S,DK)
    ushort_t* vT  = p;  p += NM;   // (B,H,DK,S)
    ushort_t* ao  = p;  p += NM;   // (B,S,D)

    ConvArgs ca;
    ca.src[0] = Wqf;  ca.dst[0] = Wq;  ca.n[0] = (int)NW;
    ca.src[1] = Wkf;  ca.dst[1] = Wk;  ca.n[1] = (int)NW;
    ca.src[2] = Wvf;  ca.dst[2] = Wv;  ca.n[2] = (int)NW;
    ca.src[3] = Wof;  ca.dst[3] = Wo;  ca.n[3] = (int)NW;
    ca.src[4] = Wqbf; ca.dst[4] = bq;  ca.n[4] = (int)NB;
    ca.src[5] = Wkbf; ca.dst[5] = bk;  ca.n[5] = (int)NB;
    ca.src[6] = Wvbf; ca.dst[6] = bvv; ca.n[6] = (int)NB;
    ca.src[7] = Wobf; ca.dst[7] = bo;  ca.n[7] = (int)NB;

    int cum = 0;
    ca.cum[0] = 0;
    for (int i = 0; i < 8; ++i) {
        cum += (ca.n[i] + 2047) / 2048;
        ca.cum[i + 1] = cum;
    }

    dim3 blk(256);
    convert_kernel<<<dim3((unsigned)cum), blk, 0, stream>>>(ca);

    qkv_kernel<<<dim3(768), blk, 0, stream>>>(
        Qf, Kf, Vf, Wq, Wk, Wv, bq, bk, bvv, qn, kn, vT);
    attn_kernel<<<dim3(BATCH * N_HEADS, SEQ / 128), blk, 0, stream>>>(qn, kn, vT, ao);
    wo_kernel<<<dim3(256), blk, 0, stream>>>(
        ao, Wo, bo, (float*)d_out);
}

// Round 9
// 211.991 us; speedup vs baseline: 1.2157x; 1.2157x over previous
//
#include <hip/hip_runtime.h>
#include <hip/hip_bf16.h>

// Problem: B=2, S=2048, D_MODEL=1024, H=16, DK=64.
// out = ((l2norm(Q Wq^T) l2norm(K Wk^T)^T)^2 (V Wv^T)) Wo^T   (per head)
// fp32 in/out; internally bf16 MFMA with fp32 accumulation.
//
// Round 17 changes vs round 16:
//  - R16's fused fp32-A path REVERTED (measured 3x qkv regression: fp32
//    doubles staged bytes, L2 thrash, serialized pipeline). convert_kernel
//    back to all 11 tensors (flattened 1D grid).
//  - qkv: BK=32. LDS ring 32 KB (36 KB with MODE-2 overlay) ->
//    launch_bounds(256,3), 3 blocks/CU; grid 768 = EXACTLY 3/CU -> single
//    scheduling round, no tail (R14 had 2 blocks/CU, 1.5 rounds).
//    Total LDS bytes/block invariant under BK; known cost: 2x barriers
//    (covered by 12 waves/CU) + 4-way frag-read conflict (second-order).
//  - wo unchanged from R14 (BM=64, BK=64, grid 512 = 2/CU single round).
//  - attn unchanged (R1/R9 exact, best measured).

#define D_MODEL 1024
#define N_HEADS 16
#define D_K     64
#define BATCH   2
#define SEQ     2048
#define M_TOT   (BATCH * SEQ)   // 4096

typedef short  s16x8 __attribute__((ext_vector_type(8)));   // 8 bf16 = 4 VGPR
typedef short  s16x4 __attribute__((ext_vector_type(4)));   // 4 bf16 = 2 VGPR
typedef float  f32x4 __attribute__((ext_vector_type(4)));   // MFMA C/D frag
typedef unsigned short ushort_t;
typedef ushort_t us4 __attribute__((ext_vector_type(4)));
typedef ushort_t us8 __attribute__((ext_vector_type(8)));

__device__ __forceinline__ ushort_t f2bf(float f) {
    union { float f; unsigned int u; } x; x.f = f;
    unsigned int u = x.u;
    return (ushort_t)((u + 0x7fffu + ((u >> 16) & 1u)) >> 16);  // RNE
}
__device__ __forceinline__ float bf2f(ushort_t h) {
    union { unsigned int u; float f; } x; x.u = ((unsigned int)h) << 16;
    return x.f;
}
// pack two fp32 -> u32 of two bf16 (RNE)
__device__ __forceinline__ unsigned int pack2bf(float a, float b) {
    union { __hip_bfloat162 h; unsigned int u; } x;
    x.h = __float22bfloat162_rn(float2{a, b});
    return x.u;
}

// PV matrix op: K=16 bf16 MFMA (B-frag == squared QK^T D-frag, in-lane).
__device__ __forceinline__ f32x4 mfma_pv(s16x4 a, s16x4 b, f32x4 c) {
#if __has_builtin(__builtin_amdgcn_mfma_f32_16x16x16bf16_1k)
    return __builtin_amdgcn_mfma_f32_16x16x16bf16_1k(a, b, c, 0, 0, 0);
#else
    // zero-padded K=32 fallback: real data in k=quad*8+0..3 on both sides
    s16x8 a8 = {a[0], a[1], a[2], a[3], 0, 0, 0, 0};
    s16x8 b8 = {b[0], b[1], b[2], b[3], 0, 0, 0, 0};
    return __builtin_amdgcn_mfma_f32_16x16x32_bf16(a8, b8, c, 0, 0, 0);
#endif
}

// async global->LDS, 16B per lane (lane i's lds ptr == wave base + i*16).
__device__ __forceinline__ void gload_lds16(const ushort_t* g, ushort_t* l) {
    __builtin_amdgcn_global_load_lds(
        (__attribute__((address_space(1))) void*)(ushort_t*)g,
        (__attribute__((address_space(3))) void*)l, 16, 0, 0);
}

#define WAIT_VM(n)  asm volatile("s_waitcnt vmcnt(" #n ")" ::: "memory")
#define WAIT_LGKM0  asm volatile("s_waitcnt lgkmcnt(0)" ::: "memory")
#define BARRIER     asm volatile("s_barrier" ::: "memory")

// ---------------------------------------------------------------------------
// fp32 -> bf16 conversion, flattened 1D grid: block -> (tensor, chunk) via
// chunk-prefix table; 2048 elements per block (8 per thread).
// ---------------------------------------------------------------------------
struct ConvArgs {
    const float* src[11];
    ushort_t*    dst[11];
    int          n[11];
    int          cum[12];   // chunk prefix sums
};

__global__ __launch_bounds__(256) void convert_kernel(ConvArgs a) {
    const int lin = blockIdx.x;
    int t = 0;
#pragma unroll
    for (int i = 0; i < 11; ++i)
        if (lin >= a.cum[i + 1]) t = i + 1;
    const int off = (lin - a.cum[t]) * 2048 + threadIdx.x * 8;
    if (off >= a.n[t]) return;
    const float4 v0 = *(const float4*)(a.src[t] + off);
    const float4 v1 = *(const float4*)(a.src[t] + off + 4);
    us8 p;
    p[0] = f2bf(v0.x); p[1] = f2bf(v0.y); p[2] = f2bf(v0.z); p[3] = f2bf(v0.w);
    p[4] = f2bf(v1.x); p[5] = f2bf(v1.y); p[6] = f2bf(v1.z); p[7] = f2bf(v1.w);
    *(us8*)(a.dst[t] + off) = p;
}

// ---------------------------------------------------------------------------
// GEMM body BK=64 (used by wo): BM x 128 tile, 4 waves 2x2, 2-deep DMA
// pipeline, issue-early staging. MODE 0: fp32 store.
// ---------------------------------------------------------------------------
template <int BM>
__device__ __forceinline__ void gemm_body(
    ushort_t* __restrict__ smem,
    const ushort_t* __restrict__ A,
    const ushort_t* __restrict__ W,
    const ushort_t* __restrict__ bias,
    float* __restrict__ outf,
    int bx, int by)
{
    static_assert(BM == 64 || BM == 128, "");
    constexpr int K    = 1024;
    constexpr int MF   = BM / 32;
    constexpr int BUFW = (BM + 128) * 64;
    constexpr int NIT  = K / 64;

    const int t    = threadIdx.x;
    const int wave = t >> 6;
    const int lane = t & 63;
    const int quad = lane >> 4;
    const int lc   = lane & 15;
    const int wm   = wave >> 1;
    const int wn   = wave & 1;
    const int m0   = bx * BM;
    const int n0   = by * 128;

    f32x4 acc[MF][4];
    const f32x4 zero = {0.f, 0.f, 0.f, 0.f};
#pragma unroll
    for (int i = 0; i < MF; ++i)
#pragma unroll
        for (int j = 0; j < 4; ++j) acc[i][j] = zero;

    auto stage = [&](int buf, int k0) {
        ushort_t* Ast = smem + buf * BUFW;
        ushort_t* Bst = Ast + BM * 64;
#pragma unroll
        for (int c = 0; c < MF; ++c) {
            int idx = c * 256 + t;
            int row = idx >> 3, phys = idx & 7;
            int col = (phys ^ (row & 7)) * 8;
            gload_lds16(A + (size_t)(m0 + row) * K + k0 + col, Ast + idx * 8);
        }
#pragma unroll
        for (int c = 0; c < 4; ++c) {
            int idx = c * 256 + t;
            int row = idx >> 3, phys = idx & 7;
            int col = (phys ^ (row & 7)) * 8;
            gload_lds16(W + (size_t)(n0 + row) * K + k0 + col, Bst + idx * 8);
        }
    };
    auto loadfrags = [&](int buf, s16x8 (&a)[MF][2], s16x8 (&b)[4][2]) {
        ushort_t* Ast = smem + buf * BUFW;
        ushort_t* Bst = Ast + BM * 64;
#pragma unroll
        for (int ks = 0; ks < 2; ++ks) {
            const int ph = ((ks * 4 + quad) ^ (lc & 7)) * 8;
#pragma unroll
            for (int i = 0; i < MF; ++i)
                a[i][ks] = *(const s16x8*)(Ast + (wm * (BM / 2) + i * 16 + lc) * 64 + ph);
#pragma unroll
            for (int i = 0; i < 4; ++i)
                b[i][ks] = *(const s16x8*)(Bst + (wn * 64 + i * 16 + lc) * 64 + ph);
        }
    };
    auto mfmas = [&](s16x8 (&a)[MF][2], s16x8 (&b)[4][2]) {
#pragma unroll
        for (int ks = 0; ks < 2; ++ks)
#pragma unroll
            for (int mf = 0; mf < MF; ++mf)
#pragma unroll
                for (int nf = 0; nf < 4; ++nf)
                    acc[mf][nf] = __builtin_amdgcn_mfma_f32_16x16x32_bf16(
                        a[mf][ks], b[nf][ks], acc[mf][nf], 0, 0, 0);
    };

    stage(0, 0);
    stage(1, 64);
    s16x8 afr[MF][2], bfr[4][2];
    for (int it = 0; it < NIT; ++it) {
        if (it < NIT - 1) {
            if constexpr (BM == 128) WAIT_VM(8); else WAIT_VM(6);
        } else {
            WAIT_VM(0);
        }
        BARRIER;                       // tile `it` landed
        loadfrags(it & 1, afr, bfr);
        WAIT_LGKM0;
        BARRIER;                       // all waves' reads done -> buf reusable
        if (it < NIT - 2) stage(it & 1, (it + 2) * 64);   // issue-early DMA
        mfmas(afr, bfr);               // covers the DMA flight
    }

    float bv[4];
#pragma unroll
    for (int nf = 0; nf < 4; ++nf) bv[nf] = bf2f(bias[n0 + wn * 64 + nf * 16 + lc]);

#pragma unroll
    for (int mf = 0; mf < MF; ++mf)
#pragma unroll
        for (int nf = 0; nf < 4; ++nf)
#pragma unroll
            for (int r = 0; r < 4; ++r) {
                int mg = m0 + wm * (BM / 2) + mf * 16 + quad * 4 + r;
                int ng = n0 + wn * 64 + nf * 16 + lc;
                outf[(size_t)mg * D_MODEL + ng] = acc[mf][nf][r] + bv[nf];
            }
}

// ---------------------------------------------------------------------------
// GEMM body BK=32 (used by qkv): 128x128 tile, 4 waves 2x2, 2-deep pipeline,
// 32 K-steps, 16 KB/buf. LDS 32 KB ring (+ MODE2 36 KB overlay) -> 3 blk/CU.
// MODE 1: L2-norm -> (B,H,S,DK)   MODE 2: transpose -> (B,H,DK,S)
// ---------------------------------------------------------------------------
template <int MODE>
__device__ __forceinline__ void gemm_body32(
    ushort_t* __restrict__ smem,
    const ushort_t* __restrict__ A,
    const ushort_t* __restrict__ W,
    const ushort_t* __restrict__ bias,
    ushort_t* __restrict__ out,
    int bx, int by)
{
    constexpr int K    = 1024;
    constexpr int BUFW = 256 * 32;         // 8192 elems = 16 KB per buf
    constexpr int NIT  = K / 32;           // 32

    const int t    = threadIdx.x;
    const int wave = t >> 6;
    const int lane = t & 63;
    const int quad = lane >> 4;
    const int lc   = lane & 15;
    const int wm   = wave >> 1;
    const int wn   = wave & 1;
    const int m0   = bx * 128;
    const int n0   = by * 128;

    f32x4 acc[4][4];
    const f32x4 zero = {0.f, 0.f, 0.f, 0.f};
#pragma unroll
    for (int i = 0; i < 4; ++i)
#pragma unroll
        for (int j = 0; j < 4; ++j) acc[i][j] = zero;

    // rows of 32 elems = 4 chunks of 8; chunk phys holds logical phys^(row&3)
    auto stage = [&](int buf, int k0) {
        ushort_t* Ast = smem + buf * BUFW;
        ushort_t* Bst = Ast + 128 * 32;
#pragma unroll
        for (int c = 0; c < 2; ++c) {
            int idx = c * 256 + t;         // 0..511
            int row = idx >> 2, phys = idx & 3;
            int col = (phys ^ (row & 3)) * 8;
            gload_lds16(A + (size_t)(m0 + row) * K + k0 + col, Ast + idx * 8);
        }
#pragma unroll
        for (int c = 0; c < 2; ++c) {
            int idx = c * 256 + t;
            int row = idx >> 2, phys = idx & 3;
            int col = (phys ^ (row & 3)) * 8;
            gload_lds16(W + (size_t)(n0 + row) * K + k0 + col, Bst + idx * 8);
        }
    };
    auto loadfrags = [&](int buf, s16x8 (&a)[4], s16x8 (&b)[4]) {
        ushort_t* Ast = smem + buf * BUFW;
        ushort_t* Bst = Ast + 128 * 32;
#pragma unroll
        for (int i = 0; i < 4; ++i) {
            int ra = wm * 64 + i * 16 + lc;
            a[i] = *(const s16x8*)(Ast + ra * 32 + ((quad ^ (ra & 3)) * 8));
            int rb = wn * 64 + i * 16 + lc;
            b[i] = *(const s16x8*)(Bst + rb * 32 + ((quad ^ (rb & 3)) * 8));
        }
    };
    auto mfmas = [&](s16x8 (&a)[4], s16x8 (&b)[4]) {
#pragma unroll
        for (int mf = 0; mf < 4; ++mf)
#pragma unroll
            for (int nf = 0; nf < 4; ++nf)
                acc[mf][nf] = __builtin_amdgcn_mfma_f32_16x16x32_bf16(
                    a[mf], b[nf], acc[mf][nf], 0, 0, 0);
    };

    stage(0, 0);
    stage(1, 32);
    s16x8 afr[4], bfr[4];
    for (int it = 0; it < NIT; ++it) {
        if (it < NIT - 1) { WAIT_VM(4); } else { WAIT_VM(0); }
        BARRIER;                       // tile `it` landed
        loadfrags(it & 1, afr, bfr);
        WAIT_LGKM0;
        BARRIER;                       // all waves' reads done -> buf reusable
        if (it < NIT - 2) stage(it & 1, (it + 2) * 32);   // issue-early DMA
        mfmas(afr, bfr);               // covers the DMA flight
    }

    float bv[4];
#pragma unroll
    for (int nf = 0; nf < 4; ++nf) bv[nf] = bf2f(bias[n0 + wn * 64 + nf * 16 + lc]);

    if (MODE == 1) {
#pragma unroll
        for (int mf = 0; mf < 4; ++mf)
#pragma unroll
            for (int r = 0; r < 4; ++r) {
                float ss = 0.f;
#pragma unroll
                for (int nf = 0; nf < 4; ++nf) {
                    float v = acc[mf][nf][r] + bv[nf];
                    acc[mf][nf][r] = v;
                    ss += v * v;
                }
                ss += __shfl_xor(ss, 1);
                ss += __shfl_xor(ss, 2);
                ss += __shfl_xor(ss, 4);
                ss += __shfl_xor(ss, 8);
                float inv = rsqrtf(ss + 1e-8f);
                int mg = m0 + wm * 64 + mf * 16 + quad * 4 + r;
                int b  = mg >> 11;
                int s  = mg & 2047;
#pragma unroll
                for (int nf = 0; nf < 4; ++nf) {
                    int ng = n0 + wn * 64 + nf * 16 + lc;
                    int h = ng >> 6, d = ng & 63;
                    out[(((size_t)(b * N_HEADS + h)) * SEQ + s) * D_K + d] =
                        f2bf(acc[mf][nf][r] * inv);
                }
            }
    } else {
        __syncthreads();
        ushort_t* vt = smem + wave * (64 * 72);   // 4*4608 = 18432 <= smem
#pragma unroll
        for (int mf = 0; mf < 4; ++mf)
#pragma unroll
            for (int nf = 0; nf < 4; ++nf) {
                us4 p;
#pragma unroll
                for (int r = 0; r < 4; ++r) p[r] = f2bf(acc[mf][nf][r] + bv[nf]);
                *(us4*)(vt + (nf * 16 + lc) * 72 + mf * 16 + quad * 4) = p;
            }
        WAIT_LGKM0;
        __syncthreads();
#pragma unroll
        for (int r = 0; r < 8; ++r) {
            int d  = r * 8 + (lane >> 3);
            int so = (lane & 7) * 8;
            uint4 val = *(const uint4*)(vt + d * 72 + so);
            int mg = m0 + wm * 64 + so;
            int b  = mg >> 11;
            int s  = mg & 2047;
            int ng = n0 + wn * 64 + d;
            int h = ng >> 6, dh = ng & 63;
            *(uint4*)(out + (((size_t)(b * N_HEADS + h)) * D_K + dh) * SEQ + s) = val;
        }
    }
}

// qkv: 1-D grid 768 (= 256 CU x 3 blocks, single round); lin%8 = N-panel.
__global__ __launch_bounds__(256, 3) void qkv_kernel(
    const ushort_t* __restrict__ Qb, const ushort_t* __restrict__ Kb,
    const ushort_t* __restrict__ Vb,
    const ushort_t* __restrict__ Wq, const ushort_t* __restrict__ Wk,
    const ushort_t* __restrict__ Wv,
    const ushort_t* __restrict__ bq, const ushort_t* __restrict__ bk,
    const ushort_t* __restrict__ bv,
    ushort_t* __restrict__ qn, ushort_t* __restrict__ kn,
    ushort_t* __restrict__ vT)
{
    __shared__ __align__(16) ushort_t smem[18432];   // 36 KB (ring 32 KB)
    const int lin = blockIdx.x;
    const int by  = lin & 7;
    const int r   = lin >> 3;          // 0..95
    const int bx  = r & 31;
    const int z   = r >> 5;            // 0..2
    if (z == 0)
        gemm_body32<1>(smem, Qb, Wq, bq, qn, bx, by);
    else if (z == 1)
        gemm_body32<1>(smem, Kb, Wk, bk, kn, bx, by);
    else
        gemm_body32<2>(smem, Vb, Wv, bv, vT, bx, by);
}

// wo: 1-D grid 512; lin%8 = N-panel; BM=64 BK=64 (48 KB LDS).
__global__ __launch_bounds__(256) void wo_kernel(
    const ushort_t* __restrict__ A, const ushort_t* __restrict__ W,
    const ushort_t* __restrict__ bias, float* __restrict__ outf)
{
    __shared__ __align__(16) ushort_t smem[2 * (64 + 128) * 64];   // 48 KB
    const int lin = blockIdx.x;
    gemm_body<64>(smem, A, W, bias, outf, lin >> 3, lin & 7);
}

// ---------------------------------------------------------------------------
// Attention (unchanged; best measured variant): per (b,h): out = (qn kn^T)^2 v.
// Grid (x=bh 32, y=qt 16) -> 512 blocks; bh%8 XCD pin. 128 q/block.
// ---------------------------------------------------------------------------
__global__ __launch_bounds__(256, 2) void attn_kernel(
    const ushort_t* __restrict__ qn,
    const ushort_t* __restrict__ kn,
    const ushort_t* __restrict__ vT,
    ushort_t* __restrict__ attn_out)
{
    // staging buf i at smem+i*8192: kst [64 j][64 dk] + vst [64 d][64 j]
    // (both 8-el-chunk XOR-swizzled). Epilogue overlays f32 red buf.
    __shared__ __align__(16) ushort_t smem[4 * 8192];   // 64 KB

    const int t    = threadIdx.x;
    const int wave = t >> 6;
    const int lane = t & 63;
    const int quad = lane >> 4;
    const int lc   = lane & 15;
    const int bh   = blockIdx.x;       // 0..31 (bh%8 -> XCD pin)
    const int qt   = blockIdx.y;       // 0..15
    const int b    = bh >> 4;
    const int h    = bh & 15;

    const ushort_t* qb = qn + (size_t)bh * SEQ * D_K;
    const ushort_t* kb = kn + (size_t)bh * SEQ * D_K;
    const ushort_t* vb = vT + (size_t)bh * D_K * SEQ;
    const int q0 = qt * 128;

    // Q B-frags for all 8 q-tiles of this block, reused over 32 k-tiles
    s16x8 qf[8][2];
#pragma unroll
    for (int mf = 0; mf < 8; ++mf)
#pragma unroll
        for (int ks = 0; ks < 2; ++ks)
            qf[mf][ks] = *(const s16x8*)(qb + (size_t)(q0 + mf * 16 + lc) * D_K +
                                         ks * 32 + quad * 8);

    // wave's partial O^T[64 d][128 q]: oacc[df][mf], lane(lc,quad) reg r =
    // O^T[d = df*16 + quad*4 + r][q = mf*16 + lc]
    f32x4 oacc[4][8];
    const f32x4 zero = {0.f, 0.f, 0.f, 0.f};
#pragma unroll
    for (int df = 0; df < 4; ++df)
#pragma unroll
        for (int mf = 0; mf < 8; ++mf) oacc[df][mf] = zero;

    auto stage = [&](int buf, int j0) {
        ushort_t* kst = smem + buf * 8192;
        ushort_t* vst = kst + 4096;
#pragma unroll
        for (int c = 0; c < 2; ++c) {
            int idx = c * 256 + t;
            int row = idx >> 3, phys = idx & 7;
            int col = (phys ^ (row & 7)) * 8;
            gload_lds16(kb + (size_t)(j0 + row) * D_K + col, kst + idx * 8);
            gload_lds16(vb + (size_t)row * SEQ + j0 + col, vst + idx * 8);
        }
    };

    auto compute = [&](int buf) {
        ushort_t* kst = smem + buf * 8192;
        ushort_t* vst = kst + 4096;
        // K A-frags for wave's 16-j slice (K=32 over dk)
        s16x8 ak[2];
#pragma unroll
        for (int ks = 0; ks < 2; ++ks)
            ak[ks] = *(const s16x8*)(kst + (wave * 16 + lc) * 64 +
                                     (((ks * 4 + quad) ^ (lc & 7)) * 8));
        // V^T A-frags (K=16 over wave's j-slice): lane(lc,quad) needs
        // V^T[d = df*16+lc][j = wave*16 + quad*4 + 0..3] -> b64 read
        s16x4 av[4];
#pragma unroll
        for (int df = 0; df < 4; ++df) {
            const int d  = df * 16 + lc;
            const int cj = wave * 2 + (quad >> 1);        // logical 8-el chunk
            av[df] = *(const s16x4*)(vst + d * 64 + ((cj ^ (d & 7)) << 3) +
                                     ((quad & 1) << 2));
        }
#pragma unroll
        for (int mf = 0; mf < 8; ++mf) {
            f32x4 st = zero;   // S^T tile: lane = [j=quad*4+r][q=lc]
#pragma unroll
            for (int ks = 0; ks < 2; ++ks)
                st = __builtin_amdgcn_mfma_f32_16x16x32_bf16(ak[ks], qf[mf][ks],
                                                             st, 0, 0, 0);
            // square + pack: D-frag -> B-frag of K=16 MFMA, in-lane
            union { unsigned int u[2]; s16x4 v; } pb;
            pb.u[0] = pack2bf(st[0] * st[0], st[1] * st[1]);
            pb.u[1] = pack2bf(st[2] * st[2], st[3] * st[3]);
#pragma unroll
            for (int df = 0; df < 4; ++df)
                oacc[df][mf] = mfma_pv(av[df], pb.v, oacc[df][mf]);
        }
    };

    constexpr int NT = 32;
    stage(0, 0);
    stage(1, 64);
    stage(2, 128);
    for (int it = 0; it < NT; ++it) {
        if (it < NT - 2)      { WAIT_VM(8); }
        else if (it == NT - 2){ WAIT_VM(4); }
        else                  { WAIT_VM(0); }
        BARRIER;                       // tile `it` landed everywhere
        compute(it & 3);
        if (it < NT - 3) stage((it + 3) & 3, (it + 3) * 64);
    }

    // 4-wave reduction of O^T partials + store, 8 chunks of 16 q.
    // red[w][d][q], q-pitch 17 to break 4-way write aliasing. 17.4 KB.
    float* red = (float*)smem;
    constexpr int RP = 17;
#pragma unroll
    for (int mf = 0; mf < 8; ++mf) {
        BARRIER;                       // previous chunk's reads (or loop) done
#pragma unroll
        for (int df = 0; df < 4; ++df)
#pragma unroll
            for (int r = 0; r < 4; ++r)
                red[(wave * 64 + df * 16 + quad * 4 + r) * RP + lc] =
                    oacc[df][mf][r];
        WAIT_LGKM0;
        BARRIER;                       // all partials visible
#pragma unroll
        for (int qq = 0; qq < 4; ++qq) {
            const int q = wave * 4 + qq;
            const int d = lane;
            float v = red[(0 * 64 + d) * RP + q] + red[(1 * 64 + d) * RP + q] +
                      red[(2 * 64 + d) * RP + q] + red[(3 * 64 + d) * RP + q];
            const int s = q0 + mf * 16 + q;
            attn_out[((size_t)(b * SEQ + s)) * D_MODEL + h * D_K + d] = f2bf(v);
        }
    }
}

extern "C" void kernel_launch(void* const* d_in, const int* in_sizes, int n_in,
                              void* d_out, int out_size, void* d_ws, size_t ws_size,
                              hipStream_t stream)
{
    const float* Qf   = (const float*)d_in[0];
    const float* Kf   = (const float*)d_in[1];
    const float* Vf   = (const float*)d_in[2];
    const float* Wqf  = (const float*)d_in[3];
    const float* Wqbf = (const float*)d_in[4];
    const float* Wkf  = (const float*)d_in[5];
    const float* Wkbf = (const float*)d_in[6];
    const float* Wvf  = (const float*)d_in[7];
    const float* Wvbf = (const float*)d_in[8];
    const float* Wof  = (const float*)d_in[9];
    const float* Wobf = (const float*)d_in[10];

    const size_t NM = (size_t)M_TOT * D_MODEL;
    const size_t NW = (size_t)D_MODEL * D_MODEL;
    const size_t NB = D_MODEL;

    ushort_t* p = (ushort_t*)d_ws;
    ushort_t* Qb  = p;  p += NM;
    ushort_t* Kb  = p;  p += NM;
    ushort_t* Vb  = p;  p += NM;
    ushort_t* Wq  = p;  p += NW;
    ushort_t* Wk  = p;  p += NW;
    ushort_t* Wv  = p;  p += NW;
    ushort_t* Wo  = p;  p += NW;
    ushort_t* bq  = p;  p += NB;
    ushort_t* bk  = p;  p += NB;
    ushort_t* bvv = p;  p += NB;
    ushort_t* bo  = p;  p += NB;
    ushort_t* qn  = p;  p += NM;   // (B,H,S,DK)
    ushort_t* kn  = p;  p += NM;   // (B,H,S,DK)
    ushort_t* vT  = p;  p += NM;   // (B,H,DK,S)
    ushort_t* ao  = p;  p += NM;   // (B,S,D)

    ConvArgs ca;
    ca.src[0] = Qf;   ca.dst[0] = Qb;  ca.n[0] = (int)NM;
    ca.src[1] = Kf;   ca.dst[1] = Kb;  ca.n[1] = (int)NM;
    ca.src[2] = Vf;   ca.dst[2] = Vb;  ca.n[2] = (int)NM;
    ca.src[3] = Wqf;  ca.dst[3] = Wq;  ca.n[3] = (int)NW;
    ca.src[4] = Wkf;  ca.dst[4] = Wk;  ca.n[4] = (int)NW;
    ca.src[5] = Wvf;  ca.dst[5] = Wv;  ca.n[5] = (int)NW;
    ca.src[6] = Wof;  ca.dst[6] = Wo;  ca.n[6] = (int)NW;
    ca.src[7] = Wqbf; ca.dst[7] = bq;  ca.n[7] = (int)NB;
    ca.src[8] = Wkbf; ca.dst[8] = bk;  ca.n[8] = (int)NB;
    ca.src[9] = Wvbf; ca.dst[9] = bvv; ca.n[9] = (int)NB;
    ca.src[10] = Wobf; ca.dst[10] = bo; ca.n[10] = (int)NB;

    int cum = 0;
    ca.cum[0] = 0;
    for (int i = 0; i < 11; ++i) {
        cum += (ca.n[i] + 2047) / 2048;
        ca.cum[i + 1] = cum;
    }

    dim3 blk(256);
    convert_kernel<<<dim3((unsigned)cum), blk, 0, stream>>>(ca);

    qkv_kernel<<<dim3(768), blk, 0, stream>>>(
        Qb, Kb, Vb, Wq, Wk, Wv, bq, bk, bvv, qn, kn, vT);
    attn_kernel<<<dim3(BATCH * N_HEADS, SEQ / 128), blk, 0, stream>>>(qn, kn, vT, ao);
    wo_kernel<<<dim3(512), blk, 0, stream>>>(
        ao, Wo, bo, (float*)d_out);
}